// Round 1
// baseline (4061.555 us; speedup 1.0000x reference)
//
#include <hip/hip_runtime.h>
#include <hip/hip_bf16.h>

#define NN 10000
#define NE 160000
#define NBT 16          // B*T = 2*8
#define NH 2
#define CIN 15          // N_IN - 1
#define NOUT 32
#define ALPHA_F 0.2f

// ---------------- Kernel 1: dist_conv[n][h] = sum_{e: dst==n} u_dist[e]*d_ew[e][h]
__global__ void dist_scatter(const int* __restrict__ edges,
                             const float* __restrict__ dist,
                             const float* __restrict__ dew,
                             float* __restrict__ dist_conv) {
    int e = blockIdx.x * blockDim.x + threadIdx.x;
    if (e >= NE) return;
    int dst = edges[2 * e + 1];
    float d = dist[e];
    atomicAdd(&dist_conv[2 * dst + 0], d * dew[2 * e + 0]);
    atomicAdd(&dist_conv[2 * dst + 1], d * dew[2 * e + 1]);
}

// ---------------- Kernel 2: x_conv[bt][n][h][c] += d_ew[e][h] * x[bt][src][c] for dst==n
// (self-loop edges handled deterministically in finalize)
__global__ void x_scatter(const float* __restrict__ x,
                          const int* __restrict__ edges,
                          const float* __restrict__ dew,
                          float* __restrict__ xconv) {
    int e = blockIdx.x * blockDim.x + threadIdx.x;
    if (e >= NE) return;
    int bt = blockIdx.y;
    int src = edges[2 * e + 0];
    int dst = edges[2 * e + 1];
    float w0 = dew[2 * e + 0];
    float w1 = dew[2 * e + 1];
    const float* xr = x + ((size_t)bt * NN + src) * CIN;
    float* o0 = xconv + (((size_t)bt * NN + dst) * NH + 0) * CIN;
    float* o1 = o0 + CIN;
#pragma unroll
    for (int c = 0; c < CIN; ++c) {
        float xv = xr[c];
        atomicAdd(&o0[c], w0 * xv);
        atomicAdd(&o1[c], w1 * xv);
    }
}

// ---------------- Kernel 3: fused self-loop add + linear (16->32) + temporal EMA + sigmoid
// thread per (b, n, h, o); o fastest (coalesced output stores)
__global__ void finalize(const float* __restrict__ x,
                         const float* __restrict__ xconv,
                         const float* __restrict__ dist_conv,
                         const float* __restrict__ dew,
                         const float* __restrict__ W,
                         const float* __restrict__ bias,
                         float* __restrict__ out) {
    int g = blockIdx.x * blockDim.x + threadIdx.x;   // 1,280,000 threads
    int o = g & 31;
    int h = (g >> 5) & 1;
    int rest = g >> 6;           // 0..19999 = b*NN + n
    if (rest >= 2 * NN) return;
    int n = rest % NN;
    int b = rest / NN;

    float Wr[16];
#pragma unroll
    for (int c = 0; c < 16; ++c) Wr[c] = W[o * 16 + c];

    float base = bias[o] + Wr[15] * dist_conv[2 * n + h];
    float wself = dew[2 * (NE + n) + h];

    float prev = 0.f;
#pragma unroll
    for (int t = 0; t < 8; ++t) {
        size_t bt = (size_t)(b * 8 + t);
        const float* xc = xconv + ((bt * NN + n) * NH + h) * CIN;
        const float* xr = x + (bt * NN + n) * CIN;
        float y = base;
#pragma unroll
        for (int c = 0; c < CIN; ++c) y += Wr[c] * (xc[c] + wself * xr[c]);
        float v = (t == 0) ? y : (ALPHA_F * prev + (1.f - ALPHA_F) * y);
        out[((bt * NN + n) * NH + h) * NOUT + o] = 1.f / (1.f + __expf(-v));
        prev = y;
    }
}

extern "C" void kernel_launch(void* const* d_in, const int* in_sizes, int n_in,
                              void* d_out, int out_size, void* d_ws, size_t ws_size,
                              hipStream_t stream) {
    const float* x    = (const float*)d_in[0];
    // d_in[1] is T (scalar, always 8) — ignored
    const float* dew  = (const float*)d_in[2];
    const int*   edges= (const int*)d_in[3];
    const float* dist = (const float*)d_in[4];
    const float* W    = (const float*)d_in[5];
    const float* bias = (const float*)d_in[6];
    float* out = (float*)d_out;

    float* xconv     = (float*)d_ws;                      // 16*10000*2*15 = 4,800,000 floats
    float* dist_conv = xconv + (size_t)NBT * NN * NH * CIN; // +20,000 floats

    size_t zero_bytes = ((size_t)NBT * NN * NH * CIN + (size_t)NN * NH) * sizeof(float);
    hipMemsetAsync(d_ws, 0, zero_bytes, stream);

    dist_scatter<<<(NE + 255) / 256, 256, 0, stream>>>(edges, dist, dew, dist_conv);
    x_scatter<<<dim3((NE + 255) / 256, NBT), 256, 0, stream>>>(x, edges, dew, xconv);
    finalize<<<(2 * NN * NH * NOUT + 255) / 256, 256, 0, stream>>>(
        x, xconv, dist_conv, dew, W, bias, out);
}

// Round 2
// 124.242 us; speedup vs baseline: 32.6906x; 32.6906x over previous
//
#include <hip/hip_runtime.h>
#include <hip/hip_bf16.h>

#define NN 10000
#define NE 160000
#define NBT 16          // B*T = 2*8
#define NH 2
#define CIN 15          // N_IN - 1
#define NOUT 32
#define ALPHA_F 0.2f

// ---- CSR build: count degrees per destination node
__global__ void count_deg(const int* __restrict__ edges, int* __restrict__ deg) {
    int e = blockIdx.x * blockDim.x + threadIdx.x;
    if (e >= NE) return;
    atomicAdd(&deg[edges[2 * e + 1]], 1);
}

// ---- exclusive scan over 10000 degrees (single block)
__global__ __launch_bounds__(1024) void scan_rowptr(const int* __restrict__ deg,
                                                    int* __restrict__ rowptr,
                                                    int* __restrict__ cursor) {
    __shared__ int lds[1024];
    int t = threadIdx.x;
    int local[10];
    int s = 0;
    int base = t * 10;
#pragma unroll
    for (int i = 0; i < 10; ++i) {
        int idx = base + i;
        int v = (idx < NN) ? deg[idx] : 0;
        local[i] = s;
        s += v;
    }
    lds[t] = s;
    __syncthreads();
    for (int off = 1; off < 1024; off <<= 1) {
        int v = (t >= off) ? lds[t - off] : 0;
        __syncthreads();
        lds[t] += v;
        __syncthreads();
    }
    int boff = (t > 0) ? lds[t - 1] : 0;
#pragma unroll
    for (int i = 0; i < 10; ++i) {
        int idx = base + i;
        if (idx < NN) {
            rowptr[idx] = boff + local[i];
            cursor[idx] = boff + local[i];
        }
    }
    if (t == 0) rowptr[NN] = NE;
}

// ---- bin edges into CSR order (SoA payload: src, w0, w1, dist)
__global__ void bin_edges(const int* __restrict__ edges,
                          const float* __restrict__ dew,
                          const float* __restrict__ dist,
                          int* __restrict__ cursor,
                          int* __restrict__ esrc,
                          float* __restrict__ ew0,
                          float* __restrict__ ew1,
                          float* __restrict__ edist) {
    int e = blockIdx.x * blockDim.x + threadIdx.x;
    if (e >= NE) return;
    int src = edges[2 * e + 0];
    int dst = edges[2 * e + 1];
    int pos = atomicAdd(&cursor[dst], 1);
    esrc[pos] = src;
    ew0[pos] = dew[2 * e + 0];
    ew1[pos] = dew[2 * e + 1];
    edist[pos] = dist[e];
}

// ---- fused: gather messages -> LDS, then linear(16->32) + EMA + sigmoid
__global__ __launch_bounds__(256) void fused_node(const float* __restrict__ x,
                                                  const int* __restrict__ rowptr,
                                                  const int* __restrict__ esrc,
                                                  const float* __restrict__ ew0,
                                                  const float* __restrict__ ew1,
                                                  const float* __restrict__ edist,
                                                  const float* __restrict__ dew,
                                                  const float* __restrict__ W,
                                                  const float* __restrict__ bias,
                                                  float* __restrict__ out) {
    __shared__ float s_xc[NBT][NH][CIN];   // 480 floats
    __shared__ float s_dist[NH];
    __shared__ float sW[NOUT * 16];
    __shared__ float sb[NOUT];

    int n = blockIdx.x;
    int tid = threadIdx.x;

    for (int i = tid; i < NOUT * 16; i += 256) sW[i] = W[i];
    if (tid < NOUT) sb[tid] = bias[tid];

    int beg = rowptr[n];
    int end = rowptr[n + 1];

    if (tid < NBT * CIN) {                 // 240 threads: (bt, c)
        int bt = tid / CIN;
        int c = tid % CIN;
        const float* xbt = x + (size_t)bt * NN * CIN;
        float a0 = 0.f, a1 = 0.f;
        for (int k = beg; k < end; ++k) {
            int src = esrc[k];
            float xv = xbt[src * CIN + c];
            a0 += ew0[k] * xv;
            a1 += ew1[k] * xv;
        }
        float xs = xbt[n * CIN + c];       // self-loop (deterministic, not scattered)
        a0 += dew[2 * (NE + n) + 0] * xs;
        a1 += dew[2 * (NE + n) + 1] * xs;
        s_xc[bt][0][c] = a0;
        s_xc[bt][1][c] = a1;
    } else if (tid < NBT * CIN + NH) {     // 2 threads: dist_conv per head
        int h = tid - NBT * CIN;
        const float* ew = h ? ew1 : ew0;
        float s = 0.f;
        for (int k = beg; k < end; ++k) s += edist[k] * ew[k];
        s_dist[h] = s;
    }
    __syncthreads();

    if (tid < 128) {                       // (b, h, o) with o fastest
        int o = tid & 31;
        int h = (tid >> 5) & 1;
        int b = tid >> 6;
        float Wr[16];
#pragma unroll
        for (int c = 0; c < 16; ++c) Wr[c] = sW[o * 16 + c];
        float base = sb[o] + Wr[15] * s_dist[h];
        float prev = 0.f;
#pragma unroll
        for (int t = 0; t < 8; ++t) {
            int bt = b * 8 + t;
            float y = base;
#pragma unroll
            for (int c = 0; c < CIN; ++c) y += Wr[c] * s_xc[bt][h][c];
            float v = (t == 0) ? y : (ALPHA_F * prev + (1.f - ALPHA_F) * y);
            out[(((size_t)bt * NN + n) * NH + h) * NOUT + o] = 1.f / (1.f + __expf(-v));
            prev = y;
        }
    }
}

extern "C" void kernel_launch(void* const* d_in, const int* in_sizes, int n_in,
                              void* d_out, int out_size, void* d_ws, size_t ws_size,
                              hipStream_t stream) {
    const float* x     = (const float*)d_in[0];
    // d_in[1] is T (scalar, always 8) — ignored
    const float* dew   = (const float*)d_in[2];
    const int*   edges = (const int*)d_in[3];
    const float* dist  = (const float*)d_in[4];
    const float* W     = (const float*)d_in[5];
    const float* bias  = (const float*)d_in[6];
    float* out = (float*)d_out;

    // workspace layout (all 4-byte elements)
    int* deg     = (int*)d_ws;                 // [NN]
    int* rowptr  = deg + NN;                   // [NN+1]
    int* cursor  = rowptr + NN + 1;            // [NN]
    int* esrc    = cursor + NN;                // [NE]
    float* ew0   = (float*)(esrc + NE);        // [NE]
    float* ew1   = ew0 + NE;                   // [NE]
    float* edist = ew1 + NE;                   // [NE]

    hipMemsetAsync(deg, 0, NN * sizeof(int), stream);

    count_deg<<<(NE + 255) / 256, 256, 0, stream>>>(edges, deg);
    scan_rowptr<<<1, 1024, 0, stream>>>(deg, rowptr, cursor);
    bin_edges<<<(NE + 255) / 256, 256, 0, stream>>>(edges, dew, dist, cursor,
                                                    esrc, ew0, ew1, edist);
    fused_node<<<NN, 256, 0, stream>>>(x, rowptr, esrc, ew0, ew1, edist,
                                       dew, W, bias, out);
}

// Round 3
// 107.538 us; speedup vs baseline: 37.7686x; 1.1553x over previous
//
#include <hip/hip_runtime.h>
#include <hip/hip_bf16.h>

#define NN 10000
#define NE 160000
#define NBT 16          // B*T = 2*8
#define NH 2
#define CIN 15          // N_IN - 1
#define NROW (NBT*CIN)  // 240 elements per node row
#define XSTRIDE 256     // padded row stride (bf16 elems) -> 512 B, line-aligned
#define NOUT 32
#define ALPHA_F 0.2f

#define TBLK_TRANS ((NN*NBT*CIN + 255)/256)   // 9375 blocks for transpose
#define TBLK_EDGE  ((NE + 255)/256)           // 625 blocks for edge pass

__device__ __forceinline__ float bf2f(unsigned short u) {
    return __uint_as_float(((unsigned int)u) << 16);
}

// ---- prep: (a) transpose+cast x -> xh[n][bt*15+c] bf16; (b) per-edge: degree count + dist_conv atomics
__global__ __launch_bounds__(256) void prep(const float* __restrict__ x,
                                            const int* __restrict__ edges,
                                            const float* __restrict__ dist,
                                            const float* __restrict__ dew,
                                            unsigned short* __restrict__ xh,
                                            int* __restrict__ deg,
                                            float* __restrict__ dist_conv) {
    int b = blockIdx.x;
    if (b < TBLK_TRANS) {
        int i = b * 256 + threadIdx.x;
        if (i < NN * NBT * CIN) {
            int c = i % CIN;
            int rest = i / CIN;
            int n = rest % NN;
            int bt = rest / NN;
            __hip_bfloat16 h = __float2bfloat16(x[i]);
            xh[(size_t)n * XSTRIDE + bt * CIN + c] = *(unsigned short*)&h;
        }
    } else {
        int e = (b - TBLK_TRANS) * 256 + threadIdx.x;
        if (e < NE) {
            int dst = edges[2 * e + 1];
            atomicAdd(&deg[dst], 1);
            float d = dist[e];
            atomicAdd(&dist_conv[2 * dst + 0], d * dew[2 * e + 0]);
            atomicAdd(&dist_conv[2 * dst + 1], d * dew[2 * e + 1]);
        }
    }
}

// ---- exclusive scan over 10000 degrees (single block)
__global__ __launch_bounds__(1024) void scan_rowptr(const int* __restrict__ deg,
                                                    int* __restrict__ rowptr,
                                                    int* __restrict__ cursor) {
    __shared__ int lds[1024];
    int t = threadIdx.x;
    int local[10];
    int s = 0;
    int base = t * 10;
#pragma unroll
    for (int i = 0; i < 10; ++i) {
        int idx = base + i;
        int v = (idx < NN) ? deg[idx] : 0;
        local[i] = s;
        s += v;
    }
    lds[t] = s;
    __syncthreads();
    for (int off = 1; off < 1024; off <<= 1) {
        int v = (t >= off) ? lds[t - off] : 0;
        __syncthreads();
        lds[t] += v;
        __syncthreads();
    }
    int boff = (t > 0) ? lds[t - 1] : 0;
#pragma unroll
    for (int i = 0; i < 10; ++i) {
        int idx = base + i;
        if (idx < NN) {
            rowptr[idx] = boff + local[i];
            cursor[idx] = boff + local[i];
        }
    }
    if (t == 0) rowptr[NN] = NE;
}

// ---- bin edges into CSR order; payload 8 B/edge: {src, packed bf16 w0|w1}
__global__ __launch_bounds__(256) void bin_edges(const int* __restrict__ edges,
                                                 const float* __restrict__ dew,
                                                 int* __restrict__ cursor,
                                                 int2* __restrict__ epay) {
    int e = blockIdx.x * blockDim.x + threadIdx.x;
    if (e >= NE) return;
    int src = edges[2 * e + 0];
    int dst = edges[2 * e + 1];
    int pos = atomicAdd(&cursor[dst], 1);
    __hip_bfloat16 h0 = __float2bfloat16(dew[2 * e + 0]);
    __hip_bfloat16 h1 = __float2bfloat16(dew[2 * e + 1]);
    unsigned int w01 = ((unsigned int)(*(unsigned short*)&h1) << 16) | (*(unsigned short*)&h0);
    epay[pos] = make_int2(src, (int)w01);
}

// ---- fused: CSR gather (bf16, coalesced) + self-loop + linear(16->32) + EMA + sigmoid
__global__ __launch_bounds__(256) void fused_node(const unsigned short* __restrict__ xh,
                                                  const int* __restrict__ rowptr,
                                                  const int2* __restrict__ epay,
                                                  const float* __restrict__ dist_conv,
                                                  const float* __restrict__ dew,
                                                  const float* __restrict__ W,
                                                  const float* __restrict__ bias,
                                                  float* __restrict__ out) {
    __shared__ float s_xc[NBT][NH][CIN];   // 480 floats
    __shared__ float s_dist[NH];
    __shared__ float sW[NOUT * 16];
    __shared__ float sb[NOUT];

    int n = blockIdx.x;
    int tid = threadIdx.x;

    for (int i = tid; i < NOUT * 16; i += 256) sW[i] = W[i];
    if (tid < NOUT) sb[tid] = bias[tid];
    if (tid < NH) s_dist[tid] = dist_conv[2 * n + tid];

    int beg = rowptr[n];
    int end = rowptr[n + 1];

    if (tid < NROW) {                      // 240 threads: element idx = bt*15+c
        float a0 = 0.f, a1 = 0.f;
#pragma unroll 2
        for (int k = beg; k < end; ++k) {
            int2 p = epay[k];                               // broadcast (same addr all lanes)
            float xv = bf2f(xh[(size_t)p.x * XSTRIDE + tid]); // coalesced 480 B per edge
            unsigned int w = (unsigned int)p.y;
            a0 += bf2f((unsigned short)(w & 0xFFFFu)) * xv;
            a1 += bf2f((unsigned short)(w >> 16)) * xv;
        }
        float xs = bf2f(xh[(size_t)n * XSTRIDE + tid]);     // self-loop (deterministic)
        a0 += dew[2 * (NE + n) + 0] * xs;
        a1 += dew[2 * (NE + n) + 1] * xs;
        int bt = tid / CIN;
        int c = tid % CIN;
        s_xc[bt][0][c] = a0;
        s_xc[bt][1][c] = a1;
    }
    __syncthreads();

    if (tid < 128) {                       // (b, h, o) with o fastest
        int o = tid & 31;
        int h = (tid >> 5) & 1;
        int b = tid >> 6;
        float Wr[16];
#pragma unroll
        for (int c = 0; c < 16; ++c) Wr[c] = sW[o * 16 + c];
        float base = sb[o] + Wr[15] * s_dist[h];
        float prev = 0.f;
#pragma unroll
        for (int t = 0; t < 8; ++t) {
            int bt = b * 8 + t;
            float y = base;
#pragma unroll
            for (int c = 0; c < CIN; ++c) y += Wr[c] * s_xc[bt][h][c];
            float v = (t == 0) ? y : (ALPHA_F * prev + (1.f - ALPHA_F) * y);
            out[(((size_t)bt * NN + n) * NH + h) * NOUT + o] = 1.f / (1.f + __expf(-v));
            prev = y;
        }
    }
}

extern "C" void kernel_launch(void* const* d_in, const int* in_sizes, int n_in,
                              void* d_out, int out_size, void* d_ws, size_t ws_size,
                              hipStream_t stream) {
    const float* x     = (const float*)d_in[0];
    // d_in[1] is T (scalar, always 8) — ignored
    const float* dew   = (const float*)d_in[2];
    const int*   edges = (const int*)d_in[3];
    const float* dist  = (const float*)d_in[4];
    const float* W     = (const float*)d_in[5];
    const float* bias  = (const float*)d_in[6];
    float* out = (float*)d_out;

    // workspace layout
    unsigned short* xh = (unsigned short*)d_ws;            // [NN * XSTRIDE] bf16 = 5.12 MB
    int2* epay   = (int2*)(xh + (size_t)NN * XSTRIDE);     // [NE] 8 B      = 1.28 MB
    int* deg     = (int*)(epay + NE);                      // [NN]
    float* dist_conv = (float*)(deg + NN);                 // [NN*NH]
    int* rowptr  = (int*)(dist_conv + NN * NH);            // [NN+1]
    int* cursor  = rowptr + NN + 1;                        // [NN]

    // zero deg + dist_conv (contiguous, 3*NN words)
    hipMemsetAsync(deg, 0, (size_t)(NN + NN * NH) * sizeof(int), stream);

    prep<<<TBLK_TRANS + TBLK_EDGE, 256, 0, stream>>>(x, edges, dist, dew, xh, deg, dist_conv);
    scan_rowptr<<<1, 1024, 0, stream>>>(deg, rowptr, cursor);
    bin_edges<<<TBLK_EDGE, 256, 0, stream>>>(edges, dew, cursor, epay);
    fused_node<<<NN, 256, 0, stream>>>(xh, rowptr, epay, dist_conv, dew, W, bias, out);
}

// Round 4
// 104.155 us; speedup vs baseline: 38.9954x; 1.0325x over previous
//
#include <hip/hip_runtime.h>
#include <hip/hip_bf16.h>

#define NN 10000
#define NE 160000
#define NBT 16          // B*T = 2*8
#define NH 2
#define CIN 15          // N_IN - 1
#define NROW (NBT*CIN)  // 240 elements per node row
#define XSTRIDE 256     // padded row stride (bf16 elems) -> 512 B, line-aligned
#define NOUT 32
#define ALPHA_F 0.2f

#define TBLK_TRANS ((NN*NBT*CIN + 255)/256)   // 9375 blocks for transpose
#define TBLK_EDGE  ((NE + 255)/256)           // 625 blocks for edge pass

__device__ __forceinline__ float bf2f(unsigned short u) {
    return __uint_as_float(((unsigned int)u) << 16);
}

// ---- zero deg + dist_conv (3*NN words) — replaces pathologically-slow rocclr fill
__global__ __launch_bounds__(256) void zero_ws(int* __restrict__ p) {
    int i = blockIdx.x * 256 + threadIdx.x;
    if (i < 3 * NN) p[i] = 0;
}

// ---- prep: (a) transpose+cast x -> xh[n][bt*15+c] bf16; (b) per-edge: degree count + dist_conv atomics
__global__ __launch_bounds__(256) void prep(const float* __restrict__ x,
                                            const int* __restrict__ edges,
                                            const float* __restrict__ dist,
                                            const float* __restrict__ dew,
                                            unsigned short* __restrict__ xh,
                                            int* __restrict__ deg,
                                            float* __restrict__ dist_conv) {
    int b = blockIdx.x;
    if (b < TBLK_TRANS) {
        int i = b * 256 + threadIdx.x;
        if (i < NN * NBT * CIN) {
            int c = i % CIN;
            int rest = i / CIN;
            int n = rest % NN;
            int bt = rest / NN;
            __hip_bfloat16 h = __float2bfloat16(x[i]);
            xh[(size_t)n * XSTRIDE + bt * CIN + c] = *(unsigned short*)&h;
        }
    } else {
        int e = (b - TBLK_TRANS) * 256 + threadIdx.x;
        if (e < NE) {
            int dst = edges[2 * e + 1];
            atomicAdd(&deg[dst], 1);
            float d = dist[e];
            atomicAdd(&dist_conv[2 * dst + 0], d * dew[2 * e + 0]);
            atomicAdd(&dist_conv[2 * dst + 1], d * dew[2 * e + 1]);
        }
    }
}

// ---- exclusive scan over 10000 degrees (single block)
__global__ __launch_bounds__(1024) void scan_rowptr(const int* __restrict__ deg,
                                                    int* __restrict__ rowptr,
                                                    int* __restrict__ cursor) {
    __shared__ int lds[1024];
    int t = threadIdx.x;
    int local[10];
    int s = 0;
    int base = t * 10;
#pragma unroll
    for (int i = 0; i < 10; ++i) {
        int idx = base + i;
        int v = (idx < NN) ? deg[idx] : 0;
        local[i] = s;
        s += v;
    }
    lds[t] = s;
    __syncthreads();
    for (int off = 1; off < 1024; off <<= 1) {
        int v = (t >= off) ? lds[t - off] : 0;
        __syncthreads();
        lds[t] += v;
        __syncthreads();
    }
    int boff = (t > 0) ? lds[t - 1] : 0;
#pragma unroll
    for (int i = 0; i < 10; ++i) {
        int idx = base + i;
        if (idx < NN) {
            rowptr[idx] = boff + local[i];
            cursor[idx] = boff + local[i];
        }
    }
    if (t == 0) rowptr[NN] = NE;
}

// ---- bin edges into CSR order; payload 8 B/edge: {src, packed bf16 w0|w1}
__global__ __launch_bounds__(256) void bin_edges(const int* __restrict__ edges,
                                                 const float* __restrict__ dew,
                                                 int* __restrict__ cursor,
                                                 int2* __restrict__ epay) {
    int e = blockIdx.x * blockDim.x + threadIdx.x;
    if (e >= NE) return;
    int src = edges[2 * e + 0];
    int dst = edges[2 * e + 1];
    int pos = atomicAdd(&cursor[dst], 1);
    __hip_bfloat16 h0 = __float2bfloat16(dew[2 * e + 0]);
    __hip_bfloat16 h1 = __float2bfloat16(dew[2 * e + 1]);
    unsigned int w01 = ((unsigned int)(*(unsigned short*)&h1) << 16) | (*(unsigned short*)&h0);
    epay[pos] = make_int2(src, (int)w01);
}

// ---- fused: CSR gather (bf16, coalesced) + self-loop + linear(16->32) + EMA + sigmoid
__global__ __launch_bounds__(256) void fused_node(const unsigned short* __restrict__ xh,
                                                  const int* __restrict__ rowptr,
                                                  const int2* __restrict__ epay,
                                                  const float* __restrict__ dist_conv,
                                                  const float* __restrict__ dew,
                                                  const float* __restrict__ W,
                                                  const float* __restrict__ bias,
                                                  float* __restrict__ out) {
    __shared__ float s_xc[NBT][NH][CIN];   // 480 floats
    __shared__ float s_dist[NH];
    __shared__ float sW[NOUT * 16];
    __shared__ float sb[NOUT];

    int n = blockIdx.x;
    int tid = threadIdx.x;

    for (int i = tid; i < NOUT * 16; i += 256) sW[i] = W[i];
    if (tid < NOUT) sb[tid] = bias[tid];
    if (tid < NH) s_dist[tid] = dist_conv[2 * n + tid];

    int beg = rowptr[n];
    int end = rowptr[n + 1];

    if (tid < NROW) {                      // 240 threads: element idx = bt*15+c
        float a0 = 0.f, a1 = 0.f;
#pragma unroll 2
        for (int k = beg; k < end; ++k) {
            int2 p = epay[k];                               // broadcast (same addr all lanes)
            float xv = bf2f(xh[(size_t)p.x * XSTRIDE + tid]); // coalesced 480 B per edge
            unsigned int w = (unsigned int)p.y;
            a0 += bf2f((unsigned short)(w & 0xFFFFu)) * xv;
            a1 += bf2f((unsigned short)(w >> 16)) * xv;
        }
        float xs = bf2f(xh[(size_t)n * XSTRIDE + tid]);     // self-loop (deterministic)
        a0 += dew[2 * (NE + n) + 0] * xs;
        a1 += dew[2 * (NE + n) + 1] * xs;
        int bt = tid / CIN;
        int c = tid % CIN;
        s_xc[bt][0][c] = a0;
        s_xc[bt][1][c] = a1;
    }
    __syncthreads();

    if (tid < 128) {                       // (b, h, o) with o fastest
        int o = tid & 31;
        int h = (tid >> 5) & 1;
        int b = tid >> 6;
        float Wr[16];
#pragma unroll
        for (int c = 0; c < 16; ++c) Wr[c] = sW[o * 16 + c];
        float base = sb[o] + Wr[15] * s_dist[h];
        float prev = 0.f;
#pragma unroll
        for (int t = 0; t < 8; ++t) {
            int bt = b * 8 + t;
            float y = base;
#pragma unroll
            for (int c = 0; c < CIN; ++c) y += Wr[c] * s_xc[bt][h][c];
            float v = (t == 0) ? y : (ALPHA_F * prev + (1.f - ALPHA_F) * y);
            out[(((size_t)bt * NN + n) * NH + h) * NOUT + o] = 1.f / (1.f + __expf(-v));
            prev = y;
        }
    }
}

extern "C" void kernel_launch(void* const* d_in, const int* in_sizes, int n_in,
                              void* d_out, int out_size, void* d_ws, size_t ws_size,
                              hipStream_t stream) {
    const float* x     = (const float*)d_in[0];
    // d_in[1] is T (scalar, always 8) — ignored
    const float* dew   = (const float*)d_in[2];
    const int*   edges = (const int*)d_in[3];
    const float* dist  = (const float*)d_in[4];
    const float* W     = (const float*)d_in[5];
    const float* bias  = (const float*)d_in[6];
    float* out = (float*)d_out;

    // workspace layout
    unsigned short* xh = (unsigned short*)d_ws;            // [NN * XSTRIDE] bf16 = 5.12 MB
    int2* epay   = (int2*)(xh + (size_t)NN * XSTRIDE);     // [NE] 8 B      = 1.28 MB
    int* deg     = (int*)(epay + NE);                      // [NN]
    float* dist_conv = (float*)(deg + NN);                 // [NN*NH]  (contiguous after deg)
    int* rowptr  = (int*)(dist_conv + NN * NH);            // [NN+1]
    int* cursor  = rowptr + NN + 1;                        // [NN]

    zero_ws<<<(3 * NN + 255) / 256, 256, 0, stream>>>(deg);
    prep<<<TBLK_TRANS + TBLK_EDGE, 256, 0, stream>>>(x, edges, dist, dew, xh, deg, dist_conv);
    scan_rowptr<<<1, 1024, 0, stream>>>(deg, rowptr, cursor);
    bin_edges<<<TBLK_EDGE, 256, 0, stream>>>(edges, dew, cursor, epay);
    fused_node<<<NN, 256, 0, stream>>>(xh, rowptr, epay, dist_conv, dew, W, bias, out);
}